// Round 3
// 551.552 us; speedup vs baseline: 1.0269x; 1.0269x over previous
//
#include <hip/hip_runtime.h>
#include <math.h>

#define BB 16
#define SS 4096
#define DD 1024
#define ND 14
#define THRESH 0.2f

#define ADD_CH 128            // add-pass chunks per batch
#define AROWS (SS / ADD_CH)   // 32 rows per block

// native clang vector type — required by __builtin_nontemporal_load/store
typedef float vfloat4 __attribute__((ext_vector_type(4)));

// ---------------------------------------------------------------------------
// Kernel 1: partial mean-pool over S. grid = (B, chunks), block = 256.
// Block (b,c) sums rows [c*rows, c*rows+rows) of z[b] over all D (float4).
// part layout: [B][chunks][D]
// Loads are cache-allocating on purpose: z (256 MiB) == L3 size, so after
// this pass z is L3-resident for the add pass.
// ---------------------------------------------------------------------------
__global__ __launch_bounds__(256) void pool_partial(
        const float4* __restrict__ z, float4* __restrict__ part, int rows) {
    const int b = blockIdx.x;
    const int c = blockIdx.y;
    const int t = threadIdx.x;                      // 0..255 -> float4 lane over D
    const float4* p = z + ((size_t)b * SS + (size_t)c * rows) * (DD / 4) + t;
    float4 acc = {0.f, 0.f, 0.f, 0.f};
#pragma unroll 8
    for (int s = 0; s < rows; ++s) {
        float4 v = p[(size_t)s * (DD / 4)];
        acc.x += v.x; acc.y += v.y; acc.z += v.z; acc.w += v.w;
    }
    part[((size_t)b * gridDim.y + c) * (DD / 4) + t] = acc;
}

// ---------------------------------------------------------------------------
// Kernel 2: reduce partials -> pooled mean; 28 dots (wave-parallel, 7 per
// wave, shuffle-only reduction); softmax(2)=sigmoid; threshold;
// R[b][:] = sum of selected M[n][1][:]; write mlc_probs.
// grid = B, block = 256 (4 waves).
// ---------------------------------------------------------------------------
__global__ __launch_bounds__(256) void score_kernel(
        const float4* __restrict__ part, const float* __restrict__ M,
        float4* __restrict__ Rout, float* __restrict__ mlc_out, int chunks) {
    const int b = blockIdx.x;
    const int t = threadIdx.x;
    const int wave = t >> 6;          // 0..3
    const int lane = t & 63;          // 0..63

    __shared__ float pooled[DD];
    __shared__ float sc[ND * 2];
    __shared__ float hat[ND];

    // reduce partials over chunks
    float4 acc = {0.f, 0.f, 0.f, 0.f};
    const float4* p = part + (size_t)b * chunks * (DD / 4) + t;
    for (int c = 0; c < chunks; ++c) {
        float4 v = p[(size_t)c * (DD / 4)];
        acc.x += v.x; acc.y += v.y; acc.z += v.z; acc.w += v.w;
    }
    const float inv = 1.0f / (float)SS;
    ((float4*)pooled)[t] = make_float4(acc.x * inv, acc.y * inv,
                                       acc.z * inv, acc.w * inv);
    __syncthreads();

    // 28 dot products: sc[idx] = dot(pooled, M[idx]) / sqrt(D)
    // wave w owns idx = w*7 .. w*7+6; per-wave shuffle reduce, no block sync.
    for (int i = 0; i < 7; ++i) {
        const int idx = wave * 7 + i;
        const float* Mrow = M + (size_t)idx * DD;
        float partial = 0.f;
#pragma unroll
        for (int k = lane; k < DD; k += 64) partial += pooled[k] * Mrow[k];
        for (int off = 32; off > 0; off >>= 1)
            partial += __shfl_down(partial, off, 64);
        if (lane == 0) sc[idx] = partial * (1.0f / 32.0f);   // /sqrt(1024)
    }
    __syncthreads();

    if (t < ND) {
        float a1 = 1.0f / (1.0f + expf(sc[2 * t] - sc[2 * t + 1]));  // softmax[...,1]
        mlc_out[b * ND + t] = a1;
        hat[t] = (a1 > THRESH) ? 1.0f : 0.0f;
    }
    __syncthreads();

    // R[b][d] = sum_n hat[n] * M[n][1][d]
    float4 r = {0.f, 0.f, 0.f, 0.f};
    const float4* M4 = (const float4*)M;
    for (int n = 0; n < ND; ++n) {
        if (hat[n] != 0.0f) {   // wave-uniform branch
            float4 m = M4[(size_t)(n * 2 + 1) * (DD / 4) + t];
            r.x += m.x; r.y += m.y; r.z += m.z; r.w += m.w;
        }
    }
    Rout[b * (DD / 4) + t] = r;
}

// ---------------------------------------------------------------------------
// Kernel 3: z_out = z_fused + R[b][:].
// grid = (B, ADD_CH) = 2048 fat blocks; each thread holds its R lane in a
// register and streams AROWS rows. Nontemporal loads/stores: z has no reuse
// after this and out must not evict z's L3 residency mid-pass.
// ---------------------------------------------------------------------------
__global__ __launch_bounds__(256) void add_kernel(
        const vfloat4* __restrict__ z, const vfloat4* __restrict__ R,
        vfloat4* __restrict__ out) {
    const int b = blockIdx.x;
    const int c = blockIdx.y;
    const int t = threadIdx.x;
    const vfloat4 r = R[b * (DD / 4) + t];
    const size_t base = ((size_t)b * SS + (size_t)c * AROWS) * (DD / 4) + t;
#pragma unroll 8
    for (int s = 0; s < AROWS; ++s) {
        const size_t idx = base + (size_t)s * (DD / 4);
        vfloat4 v = __builtin_nontemporal_load(&z[idx]);
        v += r;
        __builtin_nontemporal_store(v, &out[idx]);
    }
}

extern "C" void kernel_launch(void* const* d_in, const int* in_sizes, int n_in,
                              void* d_out, int out_size, void* d_ws, size_t ws_size,
                              hipStream_t stream) {
    const float* z = (const float*)d_in[0];   // [B][S][D]
    const float* M = (const float*)d_in[1];   // [ND][2][D]
    float* out = (float*)d_out;               // z_out flat, then mlc_probs

    // ws layout: R [B][D] floats, then partials [B][chunks][D] floats
    float* Rws = (float*)d_ws;
    float* part = Rws + (size_t)BB * DD;
    size_t avail = ws_size > (size_t)BB * DD * sizeof(float)
                       ? ws_size - (size_t)BB * DD * sizeof(float) : 0;
    int chunks = 128;
    while (chunks > 1 && (size_t)BB * chunks * DD * sizeof(float) > avail)
        chunks >>= 1;
    if (chunks < 1) chunks = 1;
    const int rows = SS / chunks;

    pool_partial<<<dim3(BB, chunks), 256, 0, stream>>>(
        (const float4*)z, (float4*)part, rows);
    score_kernel<<<BB, 256, 0, stream>>>(
        (const float4*)part, M, (float4*)Rws,
        out + (size_t)BB * SS * DD, chunks);
    add_kernel<<<dim3(BB, ADD_CH), 256, 0, stream>>>(
        (const vfloat4*)z, (const vfloat4*)Rws, (vfloat4*)out);
}